// Round 10
// baseline (316.399 us; speedup 1.0000x reference)
//
#include <hip/hip_runtime.h>
#include <math.h>

#define NB 4096
#define NR 49
#define NS 50
#define ND 512
#define NK 100
#define NT 7            // n-tiles of 16 cols (112 >= 100); wave w owns tile w
#define KSTEPS 16       // 512 / 32
#define FRAGS (NT * KSTEPS * 64 * 8)   // 57344 ushorts (114688 B) per weight matrix

typedef __attribute__((ext_vector_type(8))) short short8;
typedef __attribute__((ext_vector_type(4))) float f32x4;

__device__ __forceinline__ unsigned short f32_bf16(float f) {
    union { float f; unsigned u; } x; x.f = f;
    return (unsigned short)((x.u + 0x7fffu + ((x.u >> 16) & 1u)) >> 16);  // RNE
}
__device__ __forceinline__ float bf16_f32(unsigned short h) {
    union { unsigned u; float f; } x; x.u = ((unsigned)h) << 16;
    return x.f;
}
__device__ __forceinline__ unsigned cvt_pk_bf16(float lo, float hi) {
    unsigned r;
    asm("v_cvt_pk_bf16_f32 %0, %1, %2" : "=v"(r) : "v"(lo), "v"(hi));
    return r;
}
__device__ __forceinline__ float fast_tanh(float x) {
    const float ax = fabsf(x);
    const float e = __expf(2.f * ax);            // inf for large ax -> r = 1
    const float r = 1.f - 2.f / (e + 1.f);
    return copysignf(r, x);
}

// ---------------------------------------------------------------------------
// Pre-pass: 2 weight matrices [512][100] f32 -> bf16 MFMA B-fragments.
// (Only w_Vi_0 / w_Vt_1 needed: broadcast conditioning branches cancel in
//  softmax; the two attention passes are fully independent.)
// frag(t, gk): lane l holds W[k = gk*32 + (l>>4)*8 + j][col = t*16 + (l&15)].
// ---------------------------------------------------------------------------
__global__ void preswz_kernel(const float* __restrict__ w0, const float* __restrict__ w1,
                              unsigned short* __restrict__ ws)
{
    const int l  = threadIdx.x;          // 64
    const int gk = blockIdx.x & 15;
    const int t  = blockIdx.x >> 4;      // 0..6
    const int m  = blockIdx.y;           // 0..1
    const float* W = m ? w1 : w0;
    const int col = t * 16 + (l & 15);
    const int k0  = gk * 32 + (l >> 4) * 8;
    unsigned short* o = ws + (size_t)m * FRAGS + ((size_t)(t * 16 + gk) * 64 + l) * 8;
#pragma unroll
    for (int j = 0; j < 8; ++j) {
        float v = (col < NK) ? W[(size_t)(k0 + j) * NK + col] : 0.f;
        o[j] = f32_bf16(v);
    }
}

// ---------------------------------------------------------------------------
// Main kernel: ONE block per batch (both passes), 512 threads (8 waves),
// 3 blocks/CU. Per pass: stage whole [rows][512] bf16 tile -> 16-kstep GEMM
// (wave w < 7 owns n-tile w, 4 row-tiles) -> epilogue -> softmax -> weighted
// sum from LDS. vi held in a register across passes; single out write.
// ---------------------------------------------------------------------------
struct SM {
    short buf[NS * ND];      // 51200 B: bf16 feature tile [50 rows][512 cols]
    float part[NT][64];      // per-wave (n-tile) row partials
    float P[64];
};

__global__ __launch_bounds__(512, 6) void coattn_main(
    const float* __restrict__ ifeat, const float* __restrict__ tfeat,
    const float* __restrict__ wPi0, const float* __restrict__ bPi0,
    const float* __restrict__ wPi1, const float* __restrict__ bPi1,
    const unsigned short* __restrict__ wsW, float* __restrict__ out)
{
    __shared__ SM sm;
    const int b = blockIdx.x, tid = threadIdx.x;
    const int lane = tid & 63, wid = tid >> 6;   // wid 0..6 = n-tile; wid 7 stages/wsums
    const int colg = lane & 15, g = lane >> 4;
    const int wch = tid >> 3, wlo = tid & 7;     // wsum column addressing

    float vi = 0.f;

    for (int pass = 0; pass < 2; ++pass) {
        const float* feat = pass ? (tfeat + (size_t)b * NS * ND)
                                 : (ifeat + (size_t)b * NR * ND);
        const int nrows  = pass ? NS : NR;
        const int nclamp = nrows - 1;
        const unsigned short* wsR = wsW + (size_t)pass * FRAGS;
        const float* wPiRow = pass ? (wPi1 + NK) : wPi0;
        const float* bvec   = pass ? bPi1 : bPi0;

        // ---- stage whole tile: global f32 -> bf16 LDS, 16B-chunk XOR swizzle
        const int nitems = nrows * 64;           // 8-float groups
        for (int it = tid; it < nitems; it += 512) {
            const int r = it >> 6, c = it & 63;
            const float* p = feat + (r << 9) + (c << 3);
            const float4 a  = *reinterpret_cast<const float4*>(p);
            const float4 b4 = *reinterpret_cast<const float4*>(p + 4);
            uint4 v;
            v.x = cvt_pk_bf16(a.x, a.y);   v.y = cvt_pk_bf16(a.z, a.w);
            v.z = cvt_pk_bf16(b4.x, b4.y); v.w = cvt_pk_bf16(b4.z, b4.w);
            *reinterpret_cast<uint4*>(&sm.buf[(r << 9) + ((c ^ (r & 7)) << 3)]) = v;
        }
        __syncthreads();

        // ---- GEMM: 16 k-steps x 4 row-tiles, 1 weight frag per kstep
        if (wid < NT) {
            int arow_[4], rswz_[4];
#pragma unroll
            for (int rt = 0; rt < 4; ++rt) {
                const int r0 = rt * 16 + colg;
                arow_[rt] = (r0 < nclamp) ? r0 : nclamp;
                rswz_[rt] = arow_[rt] & 7;
            }
            const f32x4 zero4 = {0.f, 0.f, 0.f, 0.f};
            f32x4 acc[4] = {zero4, zero4, zero4, zero4};
            const unsigned short* wl = wsR + ((size_t)wid * KSTEPS * 64 + lane) * 8;
#pragma unroll
            for (int ks = 0; ks < KSTEPS; ++ks) {
                const short8 w = *reinterpret_cast<const short8*>(wl + ks * 512);
                const int q0 = (ks << 2) + g;
#pragma unroll
                for (int rt = 0; rt < 4; ++rt) {
                    const short8 a = *reinterpret_cast<const short8*>(
                        &sm.buf[(arow_[rt] << 9) + ((q0 ^ rswz_[rt]) << 3)]);
                    acc[rt] = __builtin_amdgcn_mfma_f32_16x16x32_bf16(a, w, acc[rt], 0, 0, 0);
                }
            }

            // ---- epilogue: row partials for this wave's 16 cols
            const int col = wid * 16 + colg;
            const float w = (col < NK) ? wPiRow[col] : 0.f;
            float sp[4][4];
#pragma unroll
            for (int rt = 0; rt < 4; ++rt)
#pragma unroll
                for (int i = 0; i < 4; ++i)
                    sp[rt][i] = fast_tanh(acc[rt][i]) * w;
#pragma unroll
            for (int off = 1; off < 16; off <<= 1)
#pragma unroll
                for (int rt = 0; rt < 4; ++rt)
#pragma unroll
                    for (int i = 0; i < 4; ++i)
                        sp[rt][i] += __shfl_xor(sp[rt][i], off);
            if (colg == 0) {
#pragma unroll
                for (int rt = 0; rt < 4; ++rt)
#pragma unroll
                    for (int i = 0; i < 4; ++i)
                        sm.part[wid][rt * 16 + g * 4 + i] = sp[rt][i];
            }
        }
        __syncthreads();

        if (tid < 64) {   // softmax over rows
            float v = (tid < nrows) ? bvec[tid] : 0.f;
#pragma unroll
            for (int w = 0; w < NT; ++w) v += sm.part[w][tid];
            v = (tid < nrows) ? v : -3.0e38f;
            float mx = v;
#pragma unroll
            for (int off = 32; off; off >>= 1) mx = fmaxf(mx, __shfl_xor(mx, off));
            const float e = (tid < nrows) ? __expf(v - mx) : 0.f;
            float su = e;
#pragma unroll
            for (int off = 32; off; off >>= 1) su += __shfl_xor(su, off);
            sm.P[tid] = e / su;
        }
        __syncthreads();

        // ---- weighted sum from LDS bf16: V[tid] = sum_r P[r] * feat[r, tid]
        {
            float v = 0.f;
            for (int r = 0; r < nrows; ++r) {
                const unsigned short u = (unsigned short)
                    sm.buf[(r << 9) + ((wch ^ (r & 7)) << 3) + wlo];
                v += sm.P[r] * bf16_f32(u);
            }
            if (pass == 0) vi = v;
            else out[(size_t)b * ND + tid] = vi + v;
        }
        __syncthreads();   // buf/P reads complete before pass-1 restage
    }
}

extern "C" void kernel_launch(void* const* d_in, const int* in_sizes, int n_in,
                              void* d_out, int out_size, void* d_ws, size_t ws_size,
                              hipStream_t stream) {
    const float* ifeat = (const float*)d_in[0];
    const float* tfeat = (const float*)d_in[1];
    const float* wVi0  = (const float*)d_in[2];
    const float* wPi0  = (const float*)d_in[4];
    const float* bPi0  = (const float*)d_in[5];
    const float* wVt1  = (const float*)d_in[7];
    const float* wPi1  = (const float*)d_in[8];
    const float* bPi1  = (const float*)d_in[9];
    float* outp = (float*)d_out;
    unsigned short* wsW = (unsigned short*)d_ws;   // 2*114688 = 229376 B

    hipLaunchKernelGGL(preswz_kernel, dim3(NT * KSTEPS, 2), dim3(64), 0, stream,
                       wVi0, wVt1, wsW);
    hipLaunchKernelGGL(coattn_main, dim3(NB), dim3(512), 0, stream,
                       ifeat, tfeat, wPi0, bPi0, wPi1, bPi1, wsW, outp);
}